// Round 4
// baseline (394.675 us; speedup 1.0000x reference)
//
#include <hip/hip_runtime.h>

// Adaptive softmax NLL — merged bf16-MFMA GEMM, chunk-looped with in-register LSE.
//
// Padded reordered weight (bf16) in ws (128-row chunks):
//   head : rows [0,5120)      = weight[0:5000] ++ cluster_weight ++ pad (5003 real, 40 chunks)
//   tail1: rows [5120,15232)  = weight[5000:15000]  ++ pad (79 chunks)
//   tail2: rows [15232,30336) = weight[15000:30000] ++ pad (118 chunks)
//   tail3: rows [30336,50688) = weight[30000:50257] ++ pad (159 chunks)
// Pad rows: w=0, bias=-1e30 (vanish in exp-weighted LSE merges).
// One merged GEMM launch: block = (partition, chunk-group of 8, token-tile of 128).
// Groups per partition: {5,10,15,20} -> 50 groups x 32 worst-case tiles = 1600 blocks.

#define D 512
#define NROWS_PAD 50688
#define NTOK 4096
#define NTOKP 4736
#define HEAD_GROUPS 5
#define TAIL_GSTRIDE 20

typedef __attribute__((ext_vector_type(8))) short short8;
typedef __attribute__((ext_vector_type(4))) float f32x4;

__device__ __forceinline__ unsigned short f2bf(float f) {
    unsigned int u = __float_as_uint(f);
    u += 0x7FFFu + ((u >> 16) & 1u);
    return (unsigned short)(u >> 16);
}

__device__ __forceinline__ void gload_lds16(const void* g, void* l) {
    __builtin_amdgcn_global_load_lds(
        (const __attribute__((address_space(1))) unsigned int*)g,
        (__attribute__((address_space(3))) unsigned int*)l, 16, 0, 0);
}

// ---------------- bucket tokens by cluster (deterministic counting sort) ----------------
__global__ __launch_bounds__(256) void k_bucket(
    const int* __restrict__ target, int* __restrict__ perm,
    int* __restrict__ inv, int* __restrict__ meta)
{
    __shared__ int cnt[256][4];
    __shared__ int basesh[256][4];
    __shared__ int sTot[4], sOff[4];
    const int th = threadIdx.x;
    for (int p = th; p < NTOKP; p += 256) perm[p] = -1;
    int lc[4] = {0, 0, 0, 0};
    #pragma unroll
    for (int i = 0; i < 16; ++i) {
        int tg = target[th * 16 + i];
        int c = (tg >= 5000) + (tg >= 15000) + (tg >= 30000);
        lc[c]++;
    }
    #pragma unroll
    for (int c = 0; c < 4; ++c) cnt[th][c] = lc[c];
    __syncthreads();
    if (th < 4) {
        int tot = 0;
        for (int i = 0; i < 256; ++i) tot += cnt[i][th];
        sTot[th] = tot;
    }
    __syncthreads();
    if (th == 0) {
        int b = 0;
        for (int c = 1; c < 4; ++c) { sOff[c] = b; b += ((sTot[c] + 127) >> 7) << 7; }
        meta[0] = sTot[1]; meta[1] = sTot[2]; meta[2] = sTot[3];
        meta[3] = sOff[1]; meta[4] = sOff[2]; meta[5] = sOff[3];
        meta[6] = (sTot[1] + 127) >> 7;
        meta[7] = (sTot[2] + 127) >> 7;
        meta[8] = (sTot[3] + 127) >> 7;
    }
    __syncthreads();
    if (th >= 1 && th < 4) {
        int run = sOff[th];
        for (int i = 0; i < 256; ++i) { basesh[i][th] = run; run += cnt[i][th]; }
    }
    __syncthreads();
    int run[4];
    #pragma unroll
    for (int c = 1; c < 4; ++c) run[c] = basesh[th][c];
    for (int i = 0; i < 16; ++i) {
        int t = th * 16 + i;
        int tg = target[t];
        int c = (tg >= 5000) + (tg >= 15000) + (tg >= 30000);
        if (c > 0) { int pos = run[c]++; perm[pos] = t; inv[t] = pos; }
        else inv[t] = -1;
    }
}

// ---------------- convert / reorder / pad / gather ----------------
__global__ __launch_bounds__(128) void k_convert(
    const float* __restrict__ weight, const float* __restrict__ bias,
    const float* __restrict__ cweight, const float* __restrict__ cbias,
    const float* __restrict__ hidden, const int* __restrict__ perm,
    unsigned short* __restrict__ wsW, float* __restrict__ wsB,
    unsigned short* __restrict__ wsH, unsigned short* __restrict__ wsHc)
{
    const int r = blockIdx.x;
    const int i = threadIdx.x;   // 0..127, one float4 each
    if (r < NROWS_PAD) {
        const int pstart[4] = {0, 5120, 15232, 30336};
        const int plen[4]   = {5003, 10000, 15000, 20257};
        const int psrc[4]   = {0, 5000, 15000, 30000};
        int p = (r < 5120) ? 0 : (r < 15232) ? 1 : (r < 30336) ? 2 : 3;
        int o = r - pstart[p];
        const float* src = nullptr;
        float b = -1e30f;
        if (o < plen[p]) {
            if (p == 0 && o >= 5000) { src = cweight + (size_t)(o - 5000) * D; b = cbias[o - 5000]; }
            else { int sr = psrc[p] + o; src = weight + (size_t)sr * D; b = bias[sr]; }
        }
        float4 v = src ? ((const float4*)src)[i] : make_float4(0.f, 0.f, 0.f, 0.f);
        ushort4 u;
        u.x = f2bf(v.x); u.y = f2bf(v.y); u.z = f2bf(v.z); u.w = f2bf(v.w);
        ((ushort4*)(wsW + (size_t)r * D))[i] = u;
        if (i == 0) wsB[r] = b;
    } else if (r < NROWS_PAD + NTOK) {
        int hr = r - NROWS_PAD;
        float4 v = ((const float4*)(hidden + (size_t)hr * D))[i];
        ushort4 u;
        u.x = f2bf(v.x); u.y = f2bf(v.y); u.z = f2bf(v.z); u.w = f2bf(v.w);
        ((ushort4*)(wsH + (size_t)hr * D))[i] = u;
    } else {
        int p = r - NROWS_PAD - NTOK;       // compacted position
        int tok = perm[p];
        float4 v = (tok >= 0) ? ((const float4*)(hidden + (size_t)tok * D))[i]
                              : make_float4(0.f, 0.f, 0.f, 0.f);
        ushort4 u;
        u.x = f2bf(v.x); u.y = f2bf(v.y); u.z = f2bf(v.z); u.w = f2bf(v.w);
        ((ushort4*)(wsHc + (size_t)p * D))[i] = u;
    }
}

// ---------------- exact fp32 dots for the two needed logits ----------------
__global__ __launch_bounds__(256) void k_stash(
    const float* __restrict__ hidden, const int* __restrict__ target,
    const float* __restrict__ weight, const float* __restrict__ bias,
    const float* __restrict__ cweight, const float* __restrict__ cbias,
    float2* __restrict__ stash)
{
    const int wave = threadIdx.x >> 6, lane = threadIdx.x & 63;
    const int t = blockIdx.x * 4 + wave;
    const int tg = target[t];
    const int ci = (tg >= 5000) + (tg >= 15000) + (tg >= 30000);
    const float4* h = (const float4*)(hidden + (size_t)t * D);
    const float4* w = (const float4*)(weight + (size_t)tg * D);
    const float4* c = (const float4*)(cweight + (size_t)(ci ? 3 - ci : 0) * D);
    float dw = 0.f, dc = 0.f;
    #pragma unroll
    for (int u = 0; u < 2; ++u) {
        float4 hh = h[lane * 2 + u];
        float4 ww = w[lane * 2 + u];
        float4 cc = c[lane * 2 + u];
        dw += hh.x * ww.x + hh.y * ww.y + hh.z * ww.z + hh.w * ww.w;
        dc += hh.x * cc.x + hh.y * cc.y + hh.z * cc.z + hh.w * cc.w;
    }
    #pragma unroll
    for (int off = 1; off < 64; off <<= 1) {
        dw += __shfl_xor(dw, off, 64);
        dc += __shfl_xor(dc, off, 64);
    }
    if (lane == 0) {
        float head = ci ? dc + cbias[3 - ci] : dw + bias[tg];
        float tail = ci ? dw + bias[tg]      : 0.f;
        stash[t] = make_float2(head, tail);
    }
}

// ---------------- merged GEMM: chunk-group loop + in-register online LSE ----------------
// bid -> (partition p, chunk-group g of 8 chunks, token-tile tau of 128 tokens).
// 256 threads = 4 waves (2x2). Double-buffered LDS, global_load_lds width 16,
// T2 XOR-swizzle via pre-swizzled global source (verified R2/R3, absmax=0).
__global__ __launch_bounds__(256) void k_gemm_all(
    const unsigned short* __restrict__ wsW, const float* __restrict__ wsB,
    const unsigned short* __restrict__ wsH, const unsigned short* __restrict__ wsHc,
    float2* __restrict__ headP, float2* __restrict__ tailP,
    const int* __restrict__ meta)
{
    const int bid = blockIdx.x;
    int p, rem;
    if (bid < 160)      { p = 0; rem = bid; }
    else if (bid < 480) { p = 1; rem = bid - 160; }
    else if (bid < 960) { p = 2; rem = bid - 480; }
    else                { p = 3; rem = bid - 960; }
    const int g = rem >> 5, tau = rem & 31;

    int tokBase = 0;
    const unsigned short* H = wsH;
    if (p > 0) {
        if (tau >= meta[5 + p]) return;   // data-dependent tile count
        tokBase = meta[2 + p];
        H = wsHc;
    }
    const int chunks_[4] = {40, 79, 118, 159};
    const int pstart_[4] = {0, 5120, 15232, 30336};
    const int pstart = pstart_[p];
    const int c0 = g * 8;
    const int c1 = min(c0 + 8, chunks_[p]);

    const int tid = threadIdx.x;
    const int w = tid >> 6, lane = tid & 63;
    const int wm = w >> 1, wn = w & 1;
    const int rg = lane >> 4;

    __shared__ unsigned short ldsA[2][128 * 64];
    __shared__ unsigned short ldsB[2][128 * 64];
    __shared__ float2 sred[2][128];

    const unsigned short* Hb = H + (size_t)(tokBase + tau * 128) * D;

    auto STAGE = [&](int buf, int c, int t) {
        const unsigned short* Wb = wsW + (size_t)(pstart + c * 128) * D;
        #pragma unroll
        for (int j = 0; j < 4; ++j) {
            int e = w * 256 + j * 64 + lane;
            int r = e >> 3;
            int ck = (e & 7) ^ (r & 7);                 // inverse-swizzled source chunk
            size_t go = (size_t)r * D + (size_t)t * 64 + ck * 8;
            gload_lds16(Wb + go, &ldsA[buf][(w * 4 + j) * 512]);
            gload_lds16(Hb + go, &ldsB[buf][(w * 4 + j) * 512]);
        }
    };

    f32x4 acc[4][4];
    #pragma unroll
    for (int m = 0; m < 4; ++m)
        #pragma unroll
        for (int n = 0; n < 4; ++n) acc[m][n] = (f32x4){0.f, 0.f, 0.f, 0.f};

    float rm[4], rs[4];
    #pragma unroll
    for (int n = 0; n < 4; ++n) { rm[n] = -1e30f; rs[n] = 0.f; }

    const int xorv = (lane & 7) << 4;          // byte XOR for swizzled read
    const int rowA = wm * 64 + (lane & 15);
    const int rowB = wn * 64 + (lane & 15);
    const int kbase = rg * 16;                 // byte offset within 32-k step

    const int nsteps = (c1 - c0) * 8;
    STAGE(0, c0, 0);
    __syncthreads();

    f32x4 bb[4];
    int buf = 0;
    for (int s = 0; s < nsteps; ++s) {
        const int c = c0 + (s >> 3), t = s & 7;
        const int ns = s + 1;
        if (ns < nsteps) STAGE(buf ^ 1, c0 + (ns >> 3), ns & 7);

        if (t == 0) {   // prefetch this chunk's bias rows into regs
            #pragma unroll
            for (int m = 0; m < 4; ++m)
                bb[m] = *(const f32x4*)(wsB + pstart + c * 128 + wm * 64 + m * 16 + rg * 4);
        }

        #pragma unroll
        for (int ks = 0; ks < 2; ++ks) {
            const int koff = (ks * 64 + kbase) ^ xorv;
            short8 af[4], bfr[4];
            #pragma unroll
            for (int m = 0; m < 4; ++m)
                af[m] = *(const short8*)((const char*)&ldsA[buf][0] + (rowA + m * 16) * 128 + koff);
            #pragma unroll
            for (int n = 0; n < 4; ++n)
                bfr[n] = *(const short8*)((const char*)&ldsB[buf][0] + (rowB + n * 16) * 128 + koff);
            #pragma unroll
            for (int m = 0; m < 4; ++m)
                #pragma unroll
                for (int n = 0; n < 4; ++n)
                    acc[m][n] = __builtin_amdgcn_mfma_f32_16x16x32_bf16(af[m], bfr[n], acc[m][n], 0, 0, 0);
        }

        if (t == 7) {   // fold chunk into running per-token (m,s); register-only
            #pragma unroll
            for (int n = 0; n < 4; ++n) {
                float localm = -1e30f;
                float l[4][4];
                #pragma unroll
                for (int m = 0; m < 4; ++m)
                    #pragma unroll
                    for (int j = 0; j < 4; ++j) {
                        l[m][j] = acc[m][n][j] + bb[m][j];
                        localm = fmaxf(localm, l[m][j]);
                    }
                float M = fmaxf(rm[n], localm);
                float add = 0.f;
                #pragma unroll
                for (int m = 0; m < 4; ++m)
                    #pragma unroll
                    for (int j = 0; j < 4; ++j)
                        add += __expf(l[m][j] - M);
                rs[n] = rs[n] * __expf(rm[n] - M) + add;
                rm[n] = M;
                #pragma unroll
                for (int m = 0; m < 4; ++m) acc[m][n] = (f32x4){0.f, 0.f, 0.f, 0.f};
            }
        }
        __syncthreads();
        buf ^= 1;
    }

    // block-level merge: butterfly across the 4 lane-groups, then across wm via LDS
    #pragma unroll
    for (int n = 0; n < 4; ++n) {
        #pragma unroll
        for (int off = 16; off < 64; off <<= 1) {
            float m2 = __shfl_xor(rm[n], off, 64);
            float s2 = __shfl_xor(rs[n], off, 64);
            float M = fmaxf(rm[n], m2);
            rs[n] = rs[n] * __expf(rm[n] - M) + s2 * __expf(m2 - M);
            rm[n] = M;
        }
        if (lane < 16)
            sred[wm][wn * 64 + n * 16 + lane] = make_float2(rm[n], rs[n]);
    }
    __syncthreads();
    if (tid < 128) {
        float2 p0 = sred[0][tid], p1 = sred[1][tid];
        float M = fmaxf(p0.x, p1.x);
        float S = p0.y * __expf(p0.x - M) + p1.y * __expf(p1.x - M);
        if (p == 0)
            headP[(size_t)(tau * 128 + tid) * HEAD_GROUPS + g] = make_float2(M, S);
        else
            tailP[(size_t)(tokBase + tau * 128 + tid) * TAIL_GSTRIDE + g] = make_float2(M, S);
    }
}

// ---------------- merge partials -> nll ----------------
__global__ __launch_bounds__(256) void k_stageB(
    const float2* __restrict__ headP, const float2* __restrict__ tailP,
    const float2* __restrict__ stash, const int* __restrict__ target,
    const int* __restrict__ inv, float* __restrict__ out)
{
    const int wave = threadIdx.x >> 6, lane = threadIdx.x & 63;
    const int t = blockIdx.x * 4 + wave;
    const int tg = target[t];
    const int ci = (tg >= 5000) + (tg >= 15000) + (tg >= 30000);

    float m = -1e30f, s = 0.f;
    if (lane < HEAD_GROUPS) { float2 p = headP[(size_t)t * HEAD_GROUPS + lane]; m = p.x; s = p.y; }
    #pragma unroll
    for (int off = 1; off < 64; off <<= 1) {
        float m2 = __shfl_xor(m, off, 64);
        float s2 = __shfl_xor(s, off, 64);
        float M = fmaxf(m, m2);
        s = s * __expf(m - M) + s2 * __expf(m2 - M);
        m = M;
    }
    float2 st = stash[t];
    float nll = (m + __logf(s)) - st.x;

    if (ci) {
        const int ngr_[4] = {0, 10, 15, 20};
        const int ngr = ngr_[ci];
        const int pos = inv[t];
        float m2 = -1e30f, s2 = 0.f;
        if (lane < ngr) { float2 p = tailP[(size_t)pos * TAIL_GSTRIDE + lane]; m2 = p.x; s2 = p.y; }
        #pragma unroll
        for (int off = 1; off < 64; off <<= 1) {
            float mm = __shfl_xor(m2, off, 64);
            float ss = __shfl_xor(s2, off, 64);
            float M = fmaxf(m2, mm);
            s2 = s2 * __expf(m2 - M) + ss * __expf(mm - M);
            m2 = M;
        }
        nll += (m2 + __logf(s2)) - st.y;
    }
    if (lane == 0) out[t] = nll;
}

extern "C" void kernel_launch(void* const* d_in, const int* in_sizes, int n_in,
                              void* d_out, int out_size, void* d_ws, size_t ws_size,
                              hipStream_t stream) {
    const float* hidden  = (const float*)d_in[0];
    const int*   targetp = (const int*)d_in[1];
    const float* weight  = (const float*)d_in[2];
    const float* biasp   = (const float*)d_in[3];
    const float* cweight = (const float*)d_in[4];
    const float* cbias   = (const float*)d_in[5];
    float* outp = (float*)d_out;

    char* ws = (char*)d_ws;
    unsigned short* wsW   = (unsigned short*)(ws);                 // 51,904,512 B
    float*          wsB   = (float*)(ws + 51904512);               //    202,752 B
    unsigned short* wsH   = (unsigned short*)(ws + 52107264);      //  4,194,304 B
    unsigned short* wsHc  = (unsigned short*)(ws + 56301568);      //  4,849,664 B
    float2*         headP = (float2*)(ws + 61151232);              //    163,840 B
    float2*         tailP = (float2*)(ws + 61315072);              //    757,760 B
    float2*         wsS   = (float2*)(ws + 62072832);              //     32,768 B
    int*            perm  = (int*)(ws + 62105600);                 //     18,944 B
    int*            inv   = (int*)(ws + 62124544);                 //     16,384 B
    int*            meta  = (int*)(ws + 62140928);                 //         64 B

    k_bucket<<<1, 256, 0, stream>>>(targetp, perm, inv, meta);
    k_convert<<<NROWS_PAD + NTOK + NTOKP, 128, 0, stream>>>(
        weight, biasp, cweight, cbias, hidden, perm, wsW, wsB, wsH, wsHc);
    k_stash<<<NTOK / 4, 256, 0, stream>>>(hidden, targetp, weight, biasp,
                                          cweight, cbias, wsS);
    k_gemm_all<<<1600, 256, 0, stream>>>(wsW, wsB, wsH, wsHc, headP, tailP, meta);
    k_stageB<<<NTOK / 4, 256, 0, stream>>>(headP, tailP, wsS, targetp, inv, outp);
}

// Round 5
// 279.369 us; speedup vs baseline: 1.4127x; 1.4127x over previous
//
#include <hip/hip_runtime.h>

// Adaptive softmax NLL — 256x256 deep-pipelined bf16-MFMA GEMM (counted vmcnt),
// merged single launch, per-block LSE epilogue.
//
// Padded reordered weight (bf16) in ws (256-row tiles):
//   head : rows [0,5120)      = weight[0:5000] ++ cluster_weight ++ pad (20 tiles)
//   tail1: rows [5120,15360)  = weight[5000:15000]  ++ pad (40 tiles)
//   tail2: rows [15360,30464) = weight[15000:30000] ++ pad (59 tiles)
//   tail3: rows [30464,50944) = weight[30000:50257] ++ pad (80 tiles)
// Pad rows: w=0, bias=-1e30 (vanish in exp-weighted LSE merges).
// Buckets of tail tokens padded to 256.

#define D 512
#define NROWS_PAD 50944
#define NTOK 4096
#define NTOKP 4864
#define HEAD_TILES 20
#define TAIL_PSTRIDE 80

typedef __attribute__((ext_vector_type(8))) short short8;
typedef __attribute__((ext_vector_type(4))) float f32x4;

__device__ __forceinline__ unsigned short f2bf(float f) {
    unsigned int u = __float_as_uint(f);
    u += 0x7FFFu + ((u >> 16) & 1u);
    return (unsigned short)(u >> 16);
}

__device__ __forceinline__ void gload_lds16(const void* g, void* l) {
    __builtin_amdgcn_global_load_lds(
        (const __attribute__((address_space(1))) unsigned int*)g,
        (__attribute__((address_space(3))) unsigned int*)l, 16, 0, 0);
}

// ---------------- bucket tokens by cluster (deterministic counting sort) ----------------
__global__ __launch_bounds__(256) void k_bucket(
    const int* __restrict__ target, int* __restrict__ perm,
    int* __restrict__ inv, int* __restrict__ meta)
{
    __shared__ int cnt[256][4];
    __shared__ int basesh[256][4];
    __shared__ int sTot[4], sOff[4];
    const int th = threadIdx.x;
    for (int p = th; p < NTOKP; p += 256) perm[p] = -1;
    int lc[4] = {0, 0, 0, 0};
    #pragma unroll
    for (int i = 0; i < 16; ++i) {
        int tg = target[th * 16 + i];
        int c = (tg >= 5000) + (tg >= 15000) + (tg >= 30000);
        lc[c]++;
    }
    #pragma unroll
    for (int c = 0; c < 4; ++c) cnt[th][c] = lc[c];
    __syncthreads();
    if (th < 4) {
        int tot = 0;
        for (int i = 0; i < 256; ++i) tot += cnt[i][th];
        sTot[th] = tot;
    }
    __syncthreads();
    if (th == 0) {
        int b = 0;
        for (int c = 1; c < 4; ++c) { sOff[c] = b; b += ((sTot[c] + 255) >> 8) << 8; }
        meta[0] = sTot[1]; meta[1] = sTot[2]; meta[2] = sTot[3];
        meta[3] = sOff[1]; meta[4] = sOff[2]; meta[5] = sOff[3];
        meta[6] = (sTot[1] + 255) >> 8;
        meta[7] = (sTot[2] + 255) >> 8;
        meta[8] = (sTot[3] + 255) >> 8;
    }
    __syncthreads();
    if (th >= 1 && th < 4) {
        int run = sOff[th];
        for (int i = 0; i < 256; ++i) { basesh[i][th] = run; run += cnt[i][th]; }
    }
    __syncthreads();
    int run[4];
    #pragma unroll
    for (int c = 1; c < 4; ++c) run[c] = basesh[th][c];
    for (int i = 0; i < 16; ++i) {
        int t = th * 16 + i;
        int tg = target[t];
        int c = (tg >= 5000) + (tg >= 15000) + (tg >= 30000);
        if (c > 0) { int pos = run[c]++; perm[pos] = t; inv[t] = pos; }
        else inv[t] = -1;
    }
}

// ---------------- convert / reorder / pad / gather ----------------
__global__ __launch_bounds__(128) void k_convert(
    const float* __restrict__ weight, const float* __restrict__ bias,
    const float* __restrict__ cweight, const float* __restrict__ cbias,
    const float* __restrict__ hidden, const int* __restrict__ perm,
    unsigned short* __restrict__ wsW, float* __restrict__ wsB,
    unsigned short* __restrict__ wsH, unsigned short* __restrict__ wsHc)
{
    const int r = blockIdx.x;
    const int i = threadIdx.x;   // 0..127, one float4 each
    if (r < NROWS_PAD) {
        const int pstart[4] = {0, 5120, 15360, 30464};
        const int plen[4]   = {5003, 10000, 15000, 20257};
        const int psrc[4]   = {0, 5000, 15000, 30000};
        int p = (r < 5120) ? 0 : (r < 15360) ? 1 : (r < 30464) ? 2 : 3;
        int o = r - pstart[p];
        const float* src = nullptr;
        float b = -1e30f;
        if (o < plen[p]) {
            if (p == 0 && o >= 5000) { src = cweight + (size_t)(o - 5000) * D; b = cbias[o - 5000]; }
            else { int sr = psrc[p] + o; src = weight + (size_t)sr * D; b = bias[sr]; }
        }
        float4 v = src ? ((const float4*)src)[i] : make_float4(0.f, 0.f, 0.f, 0.f);
        ushort4 u;
        u.x = f2bf(v.x); u.y = f2bf(v.y); u.z = f2bf(v.z); u.w = f2bf(v.w);
        ((ushort4*)(wsW + (size_t)r * D))[i] = u;
        if (i == 0) wsB[r] = b;
    } else if (r < NROWS_PAD + NTOK) {
        int hr = r - NROWS_PAD;
        float4 v = ((const float4*)(hidden + (size_t)hr * D))[i];
        ushort4 u;
        u.x = f2bf(v.x); u.y = f2bf(v.y); u.z = f2bf(v.z); u.w = f2bf(v.w);
        ((ushort4*)(wsH + (size_t)hr * D))[i] = u;
    } else {
        int p = r - NROWS_PAD - NTOK;       // compacted position
        int tok = perm[p];
        float4 v = (tok >= 0) ? ((const float4*)(hidden + (size_t)tok * D))[i]
                              : make_float4(0.f, 0.f, 0.f, 0.f);
        ushort4 u;
        u.x = f2bf(v.x); u.y = f2bf(v.y); u.z = f2bf(v.z); u.w = f2bf(v.w);
        ((ushort4*)(wsHc + (size_t)p * D))[i] = u;
    }
}

// ---------------- exact fp32 dots for the two needed logits ----------------
__global__ __launch_bounds__(256) void k_stash(
    const float* __restrict__ hidden, const int* __restrict__ target,
    const float* __restrict__ weight, const float* __restrict__ bias,
    const float* __restrict__ cweight, const float* __restrict__ cbias,
    float2* __restrict__ stash)
{
    const int wave = threadIdx.x >> 6, lane = threadIdx.x & 63;
    const int t = blockIdx.x * 4 + wave;
    const int tg = target[t];
    const int ci = (tg >= 5000) + (tg >= 15000) + (tg >= 30000);
    const float4* h = (const float4*)(hidden + (size_t)t * D);
    const float4* w = (const float4*)(weight + (size_t)tg * D);
    const float4* c = (const float4*)(cweight + (size_t)(ci ? 3 - ci : 0) * D);
    float dw = 0.f, dc = 0.f;
    #pragma unroll
    for (int u = 0; u < 2; ++u) {
        float4 hh = h[lane * 2 + u];
        float4 ww = w[lane * 2 + u];
        float4 cc = c[lane * 2 + u];
        dw += hh.x * ww.x + hh.y * ww.y + hh.z * ww.z + hh.w * ww.w;
        dc += hh.x * cc.x + hh.y * cc.y + hh.z * cc.z + hh.w * cc.w;
    }
    #pragma unroll
    for (int off = 1; off < 64; off <<= 1) {
        dw += __shfl_xor(dw, off, 64);
        dc += __shfl_xor(dc, off, 64);
    }
    if (lane == 0) {
        float head = ci ? dc + cbias[3 - ci] : dw + bias[tg];
        float tail = ci ? dw + bias[tg]      : 0.f;
        stash[t] = make_float2(head, tail);
    }
}

// ---------------- 256x256 deep-pipelined GEMM + per-block LSE ----------------
// 512 threads = 8 waves (2M x 4N). BK=64, dbuf LDS 128KB, counted vmcnt(8).
// Per iteration kt: vmcnt(8)->barrier->4 phases{4 ds_read + 16 MFMA w/ setprio}
// ->barrier->STAGE(kt+2). Loads for kt+1 remain in flight across barriers.
__global__ __launch_bounds__(512, 2) void k_gemm_all(
    const unsigned short* __restrict__ wsW, const float* __restrict__ wsB,
    const unsigned short* __restrict__ wsH, const unsigned short* __restrict__ wsHc,
    float2* __restrict__ headP, float2* __restrict__ tailP,
    const int* __restrict__ meta)
{
    const int bid = blockIdx.x;
    int p, rem;
    if (bid < 320)       { p = 0; rem = bid; }
    else if (bid < 960)  { p = 1; rem = bid - 320; }
    else if (bid < 1904) { p = 2; rem = bid - 960; }
    else                 { p = 3; rem = bid - 1904; }
    const int rt = rem >> 4, tau = rem & 15;

    int tokBucket = 0;
    const unsigned short* H = wsH;
    if (p > 0) {
        if (tau >= meta[5 + p]) return;      // data-dependent token-tile count
        tokBucket = meta[2 + p];
        H = wsHc;
    }
    const int pstart_[4] = {0, 5120, 15360, 30464};
    const int rowBase = pstart_[p] + rt * 256;

    const int tid = threadIdx.x;
    const int w = tid >> 6, lane = tid & 63;
    const int wm = w >> 2, wn = w & 3;          // 2M x 4N
    const int lm = lane & 15, kg = lane >> 4;

    __shared__ unsigned short ldsA[2][256 * 64];
    __shared__ unsigned short ldsB[2][256 * 64];
    __shared__ float2 sred[2][256];

    const unsigned short* Wb = wsW + (size_t)rowBase * D;
    const unsigned short* Hb = H + (size_t)(tokBucket + tau * 256) * D;

    auto STAGE = [&](int buf, int kt) {
        #pragma unroll
        for (int j = 0; j < 4; ++j) {
            int e = j * 512 + tid;               // 0..2047 16B-elements
            int r = e >> 3;                      // row 0..255
            int ck = (e & 7) ^ (r & 7);          // inverse-swizzled source chunk
            size_t go = (size_t)r * D + (size_t)kt * 64 + ck * 8;
            gload_lds16(Wb + go, &ldsA[buf][(size_t)e * 8]);
            gload_lds16(Hb + go, &ldsB[buf][(size_t)e * 8]);
        }
    };

    f32x4 acc[8][4];
    #pragma unroll
    for (int i = 0; i < 8; ++i)
        #pragma unroll
        for (int n = 0; n < 4; ++n) acc[i][n] = (f32x4){0.f, 0.f, 0.f, 0.f};

    STAGE(0, 0);
    STAGE(1, 1);                                 // 16 loads/thread outstanding

    for (int kt = 0; kt < 8; ++kt) {
        const int buf = kt & 1;
        if (kt < 7) asm volatile("s_waitcnt vmcnt(8)" ::: "memory");
        else        asm volatile("s_waitcnt vmcnt(0)" ::: "memory");
        __builtin_amdgcn_s_barrier();
        asm volatile("" ::: "memory");

        // B fragments for this wave's 64 tokens (kept in regs across phases)
        short8 Bfr[4][2];
        #pragma unroll
        for (int n = 0; n < 4; ++n)
            #pragma unroll
            for (int ks = 0; ks < 2; ++ks) {
                int tb = wn * 64 + n * 16 + lm;
                int koff = (ks * 64 + kg * 16) ^ ((tb & 7) << 4);
                Bfr[n][ks] = *(const short8*)((const char*)&ldsB[buf][0] + tb * 128 + koff);
            }
        #pragma unroll
        for (int ph = 0; ph < 4; ++ph) {
            short8 Af[2][2];
            #pragma unroll
            for (int d = 0; d < 2; ++d)
                #pragma unroll
                for (int ks = 0; ks < 2; ++ks) {
                    int ra = wm * 128 + (ph * 2 + d) * 16 + lm;
                    int koff = (ks * 64 + kg * 16) ^ ((ra & 7) << 4);
                    Af[d][ks] = *(const short8*)((const char*)&ldsA[buf][0] + ra * 128 + koff);
                }
            __builtin_amdgcn_s_setprio(1);
            #pragma unroll
            for (int d = 0; d < 2; ++d)
                #pragma unroll
                for (int n = 0; n < 4; ++n)
                    #pragma unroll
                    for (int ks = 0; ks < 2; ++ks)
                        acc[ph * 2 + d][n] = __builtin_amdgcn_mfma_f32_16x16x32_bf16(
                            Af[d][ks], Bfr[n][ks], acc[ph * 2 + d][n], 0, 0, 0);
            __builtin_amdgcn_s_setprio(0);
        }

        asm volatile("" ::: "memory");
        __builtin_amdgcn_s_barrier();            // all reads of buf done
        asm volatile("" ::: "memory");
        if (kt + 2 < 8) STAGE(buf, kt + 2);      // refill freed buffer
    }

    // ---- epilogue: bias add + per-token LSE over this block's 256 rows ----
    #pragma unroll
    for (int i = 0; i < 8; ++i) {
        f32x4 bb = *(const f32x4*)(wsB + rowBase + wm * 128 + i * 16 + kg * 4);
        #pragma unroll
        for (int n = 0; n < 4; ++n)
            #pragma unroll
            for (int j = 0; j < 4; ++j)
                acc[i][n][j] += bb[j];
    }
    #pragma unroll
    for (int n = 0; n < 4; ++n) {
        float mval = -1e30f;
        #pragma unroll
        for (int i = 0; i < 8; ++i)
            #pragma unroll
            for (int j = 0; j < 4; ++j)
                mval = fmaxf(mval, acc[i][n][j]);
        float sval = 0.f;
        #pragma unroll
        for (int i = 0; i < 8; ++i)
            #pragma unroll
            for (int j = 0; j < 4; ++j)
                sval += __expf(acc[i][n][j] - mval);
        #pragma unroll
        for (int off = 16; off < 64; off <<= 1) {
            float m2 = __shfl_xor(mval, off, 64);
            float s2 = __shfl_xor(sval, off, 64);
            float M = fmaxf(mval, m2);
            sval = sval * __expf(mval - M) + s2 * __expf(m2 - M);
            mval = M;
        }
        if (lane < 16)
            sred[wm][wn * 64 + n * 16 + lane] = make_float2(mval, sval);
    }
    __syncthreads();
    if (tid < 256) {
        float2 p0 = sred[0][tid], p1 = sred[1][tid];
        float M = fmaxf(p0.x, p1.x);
        float S = p0.y * __expf(p0.x - M) + p1.y * __expf(p1.x - M);
        if (p == 0)
            headP[(size_t)(tau * 256 + tid) * HEAD_TILES + rt] = make_float2(M, S);
        else
            tailP[(size_t)(tokBucket + tau * 256 + tid) * TAIL_PSTRIDE + rt] = make_float2(M, S);
    }
}

// ---------------- merge partials -> nll ----------------
__global__ __launch_bounds__(256) void k_stageB(
    const float2* __restrict__ headP, const float2* __restrict__ tailP,
    const float2* __restrict__ stash, const int* __restrict__ target,
    const int* __restrict__ inv, float* __restrict__ out)
{
    const int wave = threadIdx.x >> 6, lane = threadIdx.x & 63;
    const int t = blockIdx.x * 4 + wave;
    const int tg = target[t];
    const int ci = (tg >= 5000) + (tg >= 15000) + (tg >= 30000);

    float m = -1e30f, s = 0.f;
    if (lane < HEAD_TILES) { float2 p = headP[(size_t)t * HEAD_TILES + lane]; m = p.x; s = p.y; }
    #pragma unroll
    for (int off = 1; off < 64; off <<= 1) {
        float m2 = __shfl_xor(m, off, 64);
        float s2 = __shfl_xor(s, off, 64);
        float M = fmaxf(m, m2);
        s = s * __expf(m - M) + s2 * __expf(m2 - M);
        m = M;
    }
    float2 st = stash[t];
    float nll = (m + __logf(s)) - st.x;

    if (ci) {
        const int ntl_[4] = {0, 40, 59, 80};
        const int ntl = ntl_[ci];
        const int pos = inv[t];
        float m2 = -1e30f, s2 = 0.f;
        for (int c = lane; c < ntl; c += 64) {
            float2 p = tailP[(size_t)pos * TAIL_PSTRIDE + c];
            float M = fmaxf(m2, p.x);
            s2 = s2 * __expf(m2 - M) + p.y * __expf(p.x - M);
            m2 = M;
        }
        #pragma unroll
        for (int off = 1; off < 64; off <<= 1) {
            float mm = __shfl_xor(m2, off, 64);
            float ss = __shfl_xor(s2, off, 64);
            float M = fmaxf(m2, mm);
            s2 = s2 * __expf(m2 - M) + ss * __expf(mm - M);
            m2 = M;
        }
        nll += (m2 + __logf(s2)) - st.y;
    }
    if (lane == 0) out[t] = nll;
}

extern "C" void kernel_launch(void* const* d_in, const int* in_sizes, int n_in,
                              void* d_out, int out_size, void* d_ws, size_t ws_size,
                              hipStream_t stream) {
    const float* hidden  = (const float*)d_in[0];
    const int*   targetp = (const int*)d_in[1];
    const float* weight  = (const float*)d_in[2];
    const float* biasp   = (const float*)d_in[3];
    const float* cweight = (const float*)d_in[4];
    const float* cbias   = (const float*)d_in[5];
    float* outp = (float*)d_out;

    char* ws = (char*)d_ws;
    unsigned short* wsW   = (unsigned short*)(ws);                 // 52,166,656 B
    float*          wsB   = (float*)(ws + 52166656);               //    203,776 B
    unsigned short* wsH   = (unsigned short*)(ws + 52370432);      //  4,194,304 B
    unsigned short* wsHc  = (unsigned short*)(ws + 56564736);      //  4,980,736 B
    float2*         headP = (float2*)(ws + 61545472);              //    655,360 B
    float2*         tailP = (float2*)(ws + 62200832);              //  3,112,960 B
    float2*         wsS   = (float2*)(ws + 65313792);              //     32,768 B
    int*            perm  = (int*)(ws + 65346560);                 //     19,456 B
    int*            inv   = (int*)(ws + 65366016);                 //     16,384 B
    int*            meta  = (int*)(ws + 65382400);                 //         64 B

    k_bucket<<<1, 256, 0, stream>>>(targetp, perm, inv, meta);
    k_convert<<<NROWS_PAD + NTOK + NTOKP, 128, 0, stream>>>(
        weight, biasp, cweight, cbias, hidden, perm, wsW, wsB, wsH, wsHc);
    k_stash<<<NTOK / 4, 256, 0, stream>>>(hidden, targetp, weight, biasp,
                                          cweight, cbias, wsS);
    k_gemm_all<<<3184, 512, 0, stream>>>(wsW, wsB, wsH, wsHc, headP, tailP, meta);
    k_stageB<<<NTOK / 4, 256, 0, stream>>>(headP, tailP, wsS, targetp, inv, outp);
}